// Round 11
// baseline (179.633 us; speedup 1.0000x reference)
//
#include <hip/hip_runtime.h>
#include <math.h>

// SpiralNet bf16-MFMA v11: barrier-free free-running waves.
// R8==R10 (158us) with very different pipelines -> gather stream is pinned by
// per-CU line-miss concurrency (~22-28) x latency (~475cyc). Last software
// term: LDS-B chunk barriers force vmcnt(0) drains that periodically zero the
// in-flight gather population. This version removes LDS entirely:
//  - ZERO __syncthreads. Waves free-run; gather pipe never drains.
//  - B read directly from fragment-packed global BP (1KB coalesced bursts,
//    L1/L2-hot; TA cost ~= the A-gathers', affordable at these rates).
//  - depth-6 fenced gather batches (sched_barrier(0)), 4 batches for CIN=64.
//  - __launch_bounds__(256,6): VGPR cap 85 (structure ~75, no LDS) ->
//    6 blocks/CU = 24 waves/CU (grid 1563 ~ 6.1/CU, grid-limited).
// If this is neutral (>=155us), the concurrency cap is the roofline.

typedef __bf16 bf16;
typedef bf16  bf16x4 __attribute__((ext_vector_type(4)));
typedef bf16  bf16x8 __attribute__((ext_vector_type(8)));
typedef float f32x4  __attribute__((ext_vector_type(4)));

// Pack W [K][COUT] f32 into fragment-ordered bf16:
// frag q*NT+t (q = s*CC+cc); element lane*8+j of a frag is
// W[k = s*CIN + cc*32 + (lane>>4)*8 + j][col = t*16 + (lane&15)].
template<int CIN, int COUT>
__device__ inline void pack_one(const float* __restrict__ W, bf16* __restrict__ BP, int e) {
    constexpr int NT = COUT / 16, CC = CIN / 32;
    const int f = e >> 9, r = e & 511, lane = r >> 3, j = r & 7;
    const int t = f % NT, cc = (f / NT) % CC, s = f / (NT * CC);
    const int col = t * 16 + (lane & 15);
    const int k   = s * CIN + cc * 32 + (lane >> 4) * 8 + j;
    BP[e] = (bf16)W[k * COUT + col];
}

__global__ __launch_bounds__(256)
void prep_all(const float* __restrict__ x, bf16* __restrict__ xb,
              const float* __restrict__ W0, const float* __restrict__ W1,
              const float* __restrict__ W2, bf16* __restrict__ B0,
              bf16* __restrict__ B1, bf16* __restrict__ B2, int n)
{
    const int gid = blockIdx.x * 256 + threadIdx.x;
    const int e = gid * 4;
    if (e < n * 32) {
        const f32x4 v = *reinterpret_cast<const f32x4*>(x + e);
        bf16x4 o = {(bf16)v[0], (bf16)v[1], (bf16)v[2], (bf16)v[3]};
        *reinterpret_cast<bf16x4*>(xb + e) = o;
    }
    if (gid < 384 * 64)                       pack_one<32, 64>(W0, B0, gid);
    else if (gid < 384 * 64 + 768 * 64)       pack_one<64, 64>(W1, B1, gid - 384 * 64);
    else if (gid < 384 * 64 + 768 * 64 + 768 * 32)
                                              pack_one<64, 32>(W2, B2, gid - 384 * 64 - 768 * 64);
}

template<int CIN, int COUT, bool ELU, typename TOUT>
__global__ __launch_bounds__(256, 6)
void spiral_mfma(const bf16* __restrict__ h, const int* __restrict__ idx,
                 const bf16* __restrict__ BP, const float* __restrict__ bias,
                 TOUT* __restrict__ out, int n)
{
    constexpr int CC = CIN / 32;         // 32-k chunks per step (1 or 2)
    constexpr int NT = COUT / 16;        // 16-col output tiles (4,4,2)
    constexpr int TG = 12 * CC;          // total gather instrs per tile (12 or 24)
    constexpr int NB = TG / 6;           // depth-6 batches (2 or 4)

    const int lane = threadIdx.x & 63;
    const int wave = threadIdx.x >> 6;   // 0..3
    const int m    = lane & 15;
    const int quad = lane >> 4;
    const int i0   = (blockIdx.x * 4 + wave) * 16;   // MR=1: 16 rows/wave
    const bool valid = (i0 < n);                     // n%16==0: all-or-none

    // Gather indices (48B/row, 16B-aligned), clamped for tail waves.
    const int ir = min(i0 + m, n - 1);
    const int4* ip = reinterpret_cast<const int4*>(idx + (size_t)ir * 12);
    const int4 q0 = ip[0], q1 = ip[1], q2 = ip[2];
    const int rg[12] = {q0.x,q0.y,q0.z,q0.w, q1.x,q1.y,q1.z,q1.w, q2.x,q2.y,q2.z,q2.w};

    f32x4 acc[NT] = {};

    #pragma unroll
    for (int b = 0; b < NB; ++b) {
        // ---- depth-6 fenced gather batch (q ordered s-major, cc-minor) ----
        bf16x8 a[6];
        #pragma unroll
        for (int p = 0; p < 6; ++p) {
            const int q  = b * 6 + p;
            const int s  = q / CC;
            const int cc = q % CC;
            a[p] = *reinterpret_cast<const bf16x8*>(
                h + (size_t)rg[s] * CIN + cc * 32 + quad * 8);
        }
        __builtin_amdgcn_sched_barrier(0);   // all 6 issue before consumption
        // ---- consume: B from packed global (coalesced 1KB, L1/L2-hot) ----
        #pragma unroll
        for (int p = 0; p < 6; ++p) {
            const int q = b * 6 + p;
            #pragma unroll
            for (int t = 0; t < NT; ++t) {
                const bf16x8 bb = *reinterpret_cast<const bf16x8*>(
                    BP + ((size_t)(q * NT + t) * 64 + lane) * 8);
                acc[t] = __builtin_amdgcn_mfma_f32_16x16x32_bf16(a[p], bb, acc[t], 0, 0, 0);
            }
        }
    }

    if (!valid) return;

    // Epilogue: D[row = quad*4+g][col = t*16+m]; n%16==0 -> no row guards.
    #pragma unroll
    for (int t = 0; t < NT; ++t) {
        const int col = t * 16 + m;
        const float bv = bias[col];
        #pragma unroll
        for (int g = 0; g < 4; ++g) {
            const int row = i0 + quad * 4 + g;
            float v = acc[t][g] + bv;
            if (ELU) v = (v > 0.f) ? v : (__expf(v) - 1.f);
            out[(size_t)row * COUT + col] = (TOUT)v;
        }
    }
}

extern "C" void kernel_launch(void* const* d_in, const int* in_sizes, int n_in,
                              void* d_out, int out_size, void* d_ws, size_t ws_size,
                              hipStream_t stream) {
    const float* x   = (const float*)d_in[0];   // [N,32] fp32
    const int*   idx = (const int*)d_in[1];     // [N,12]
    const float* W0  = (const float*)d_in[2];   // [384,64]
    const float* b0  = (const float*)d_in[3];
    const float* W1  = (const float*)d_in[4];   // [768,64]
    const float* b1  = (const float*)d_in[5];
    const float* W2  = (const float*)d_in[6];   // [768,32]
    const float* b2  = (const float*)d_in[7];
    float* out = (float*)d_out;                 // [N,32] fp32

    const int n = in_sizes[0] / 32;             // N = 100000

    bf16* xb = (bf16*)d_ws;                     // [n,32]
    bf16* h1 = xb + (size_t)n * 32;             // [n,64]
    bf16* h2 = h1 + (size_t)n * 64;             // [n,64]
    bf16* B0 = h2 + (size_t)n * 64;             // 384*64
    bf16* B1 = B0 + 384 * 64;                   // 768*64
    bf16* B2 = B1 + 768 * 64;                   // 768*32

    const int prep_threads = n * 8;             // covers n*32/4 cvt + 98304 pack
    prep_all<<<(prep_threads + 255) / 256, dim3(256), 0, stream>>>(x, xb, W0, W1, W2, B0, B1, B2, n);

    const int grid = (n + 63) / 64;             // 4 waves x 16 rows per block
    spiral_mfma<32, 64, true,  bf16 ><<<grid, dim3(256), 0, stream>>>(xb, idx, B0, b0, h1,  n);
    spiral_mfma<64, 64, true,  bf16 ><<<grid, dim3(256), 0, stream>>>(h1, idx, B1, b1, h2,  n);
    spiral_mfma<64, 32, false, float><<<grid, dim3(256), 0, stream>>>(h2, idx, B2, b2, out, n);
}